// Round 10
// baseline (193.155 us; speedup 1.0000x reference)
//
#include <hip/hip_runtime.h>

#define NROWS 8192
#define DIM 128
#define NT 64      // 128x128 tiles per side
#define NBLK 512   // pairwise blocks; block c owns 4(+1) consecutive tiles

typedef _Float16 f16x8 __attribute__((ext_vector_type(8)));
typedef _Float16 f16x2 __attribute__((ext_vector_type(2)));
typedef float f32x16 __attribute__((ext_vector_type(16)));

#define L2E 1.4426950408889634f  // log2(e)

#define AS1(p) ((const __attribute__((address_space(1))) void*)(p))
#define AS3(p) ((__attribute__((address_space(3))) void*)(p))

// ---------------------------------------------------------------------------
// Kernel 1: per-row L2 normalize (fp32, as reference). Unchanged from R9.
// ---------------------------------------------------------------------------
__global__ __launch_bounds__(1024) void fmicl_normalize(
    const float* __restrict__ z1, const float* __restrict__ z2,
    _Float16* __restrict__ zh, float* __restrict__ sposB) {
  const int wid = threadIdx.x >> 6;
  const int lane = threadIdx.x & 63;
  const int row = blockIdx.x * 16 + wid;
  const float2 a = ((const float2*)(z1 + (size_t)row * DIM))[lane];
  const float2 b = ((const float2*)(z2 + (size_t)row * DIM))[lane];
  float s1 = a.x * a.x + a.y * a.y;
  float s2 = b.x * b.x + b.y * b.y;
#pragma unroll
  for (int off = 32; off; off >>= 1) {
    s1 += __shfl_xor(s1, off);
    s2 += __shfl_xor(s2, off);
  }
  const float inv1 = 1.0f / fmaxf(sqrtf(s1), 1e-12f);
  const float inv2 = 1.0f / fmaxf(sqrtf(s2), 1e-12f);
  const float n1x = a.x * inv1, n1y = a.y * inv1;
  const float n2x = b.x * inv2, n2y = b.y * inv2;
  const float dx = n1x - n2x, dy = n1y - n2y;
  float dp = dx * dx + dy * dy;
#pragma unroll
  for (int off = 32; off; off >>= 1) dp += __shfl_xor(dp, off);
  f16x2 h;
  h.x = (_Float16)n1x;
  h.y = (_Float16)n1y;
  *(f16x2*)(zh + (size_t)row * DIM + 2 * lane) = h;
  __shared__ float sposL[16];
  if (lane == 0)
    sposL[wid] = logf(expf(-0.5f * dp) + 1e-8f) + 1.0f;  // f'(g_pos)
  __syncthreads();
  if (threadIdx.x == 0) {
    float s = 0.0f;
#pragma unroll
    for (int k = 0; k < 16; ++k) s += sposL[k];
    sposB[blockIdx.x] = s;
  }
}

// ---------------------------------------------------------------------------
// Stage one 128-row B panel (32 KiB) into LDS via global_load_lds width=16.
// LDS dest linear; global source pre-swizzled (granule col ^= row&15);
// read side applies the same XOR (involution pair; rounds 3-9 verified).
// ---------------------------------------------------------------------------
__device__ __forceinline__ void stageB(const _Float16* __restrict__ zh,
                                       _Float16* buf, int ct, int wid,
                                       int lane) {
  const _Float16* base = zh + ((size_t)ct << 7) * DIM;
#pragma unroll
  for (int it = 0; it < 4; ++it) {
    const int P = it * 8 + wid;          // wave-uniform 4-row group 0..31
    const int R = P * 4 + (lane >> 4);   // row 0..127
    const int cs = (lane & 15) ^ (R & 15);
    __builtin_amdgcn_global_load_lds(AS1(base + (size_t)R * DIM + cs * 8),
                                     AS3(buf + P * 512), 16, 0, 0);
  }
}

// ---------------------------------------------------------------------------
// Shared body for the real pairwise kernel (V=0, REP=1) and the diagnostic
// probes. Template ablation per skill common-mistake #8 / m164 pattern:
//   V=0: full. V=1: no in-loop staging (reads stale B0; timing-only).
//   V=2: ds_reads replaced by register operand (stage+MFMA kept).
//   V=4: exp2 epilogue replaced by plain adds (MFMA+ds kept).
// All variants end in a global write; global_load_lds is side-effecting ->
// nothing DCEs (rule #17).
// ---------------------------------------------------------------------------
template <int V, int REP>
__device__ __forceinline__ void pairwise_body(const _Float16* __restrict__ zh,
                                              float* __restrict__ dst) {
  __shared__ _Float16 B0[128 * DIM];  // 32 KiB
  __shared__ _Float16 B1[128 * DIM];  // 32 KiB
  __shared__ float wsum[8];

  const int tid = threadIdx.x;
  const int lane = tid & 63;
  const int wid = tid >> 6;
  const int l31 = lane & 31;
  const int lhi = lane >> 5;
  const int m = wid >> 1;  // 0..3: 32-row block of the band
  const int n = wid & 1;   // 0..1: 64-col half of the tile

  // XCD-chunked swizzle (512 = 8*64, bijective; 260 tiles per XCD)
  const int c = (blockIdx.x & 7) * 64 + (blockIdx.x >> 3);
  const int nx = (c + 15) >> 4;  // len-5 chunks before c
  const int base = 4 * c + nx;
  const int len = 4 + ((c & 15) == 0 ? 1 : 0);

  // ---- decode base -> (rt0, ct0); C(r) = r*NT - r(r-1)/2 ----
  int rt0 = (int)(64.5f - sqrtf(64.5f * 64.5f - 2.0f * (float)base));
  if (rt0 < 0) rt0 = 0;
  while (rt0 > 0 && (rt0 * NT - (rt0 * (rt0 - 1)) / 2) > base) --rt0;
  while (((rt0 + 1) * NT - ((rt0 + 1) * rt0) / 2) <= base) ++rt0;
  const int ct0 = rt0 + (base - (rt0 * NT - (rt0 * (rt0 - 1)) / 2));

  uint4 areg[8];
  int cur_rt = -1;
  float gsum = 0.0f;

#pragma unroll 1
  for (int rep = 0; rep < REP; ++rep) {
    int rtt = rt0, ctt = ct0;
    stageB(zh, B0, ctt, wid, lane);  // prologue stage of tile 0

#pragma unroll 1
    for (int t = 0; t < len; ++t) {
      // ---- A-regs: reload only on band crossing ----
      if (rtt != cur_rt) {
        cur_rt = rtt;
        const uint4* ar =
            (const uint4*)(zh + (size_t)((rtt << 7) + m * 32 + l31) * DIM);
#pragma unroll
        for (int ks = 0; ks < 8; ++ks) areg[ks] = ar[2 * ks + lhi];
      }
      // ---- next tile coords; issue its stage before computing this one ----
      int nrt = rtt, nct = ctt + 1;
      if (nct == NT) { ++nrt; nct = nrt; }
      if constexpr (V != 1) {
        if (t + 1 < len) {
          stageB(zh, (t & 1) ? B0 : B1, nct, wid, lane);
          asm volatile("s_waitcnt vmcnt(4)" ::: "memory");
        } else {
          asm volatile("s_waitcnt vmcnt(0)" ::: "memory");
        }
      } else {
        asm volatile("s_waitcnt vmcnt(0)" ::: "memory");  // trivial after t=0
      }
      __builtin_amdgcn_s_barrier();
      __builtin_amdgcn_sched_barrier(0);

      // ---- compute: 8 K-steps, 2 B-reads -> 2 MFMA (A from registers) ----
      const uint4* B4 = (const uint4*)((V == 1) ? B0 : ((t & 1) ? B1 : B0));
      const int rb0 = n * 64 + l31;
      const int rb1 = n * 64 + 32 + l31;
      f32x16 acc0 = {}, acc1 = {};
#pragma unroll
      for (int ks = 0; ks < 8; ++ks) {
        const int kg = 2 * ks + lhi;
        uint4 vb0, vb1;
        if constexpr (V == 2) {
          vb0 = areg[ks];
          vb1 = areg[ks];
        } else {
          vb0 = B4[rb0 * 16 + (kg ^ (rb0 & 15))];
          vb1 = B4[rb1 * 16 + (kg ^ (rb1 & 15))];
        }
        const f16x8 af = __builtin_bit_cast(f16x8, areg[ks]);
        acc0 = __builtin_amdgcn_mfma_f32_32x32x16_f16(
            af, __builtin_bit_cast(f16x8, vb0), acc0, 0, 0, 0);
        acc1 = __builtin_amdgcn_mfma_f32_32x32x16_f16(
            af, __builtin_bit_cast(f16x8, vb1), acc1, 0, 0, 0);
      }

      // ---- epilogue ----
      float tsum = 0.0f;
      if constexpr (V == 4) {
#pragma unroll
        for (int r = 0; r < 16; ++r) tsum += acc0[r] + acc1[r];
      } else {
        {  // chain 0: cols [n*64, +32); diag sub-block iff m == 2n
          const bool dsub = (rtt == ctt) && (m == 2 * n);
          if (dsub) {
#pragma unroll
            for (int r = 0; r < 16; ++r) {
              const float e = __builtin_amdgcn_exp2f(fmaf(L2E, acc0[r], -L2E));
              const int mloc = (r & 3) + 4 * lhi + 8 * (r >> 2);
              tsum += (mloc != l31) ? e : 0.0f;
            }
          } else {
#pragma unroll
            for (int r = 0; r < 16; ++r)
              tsum += __builtin_amdgcn_exp2f(fmaf(L2E, acc0[r], -L2E));
          }
        }
        {  // chain 1: cols [n*64+32, +32); diag sub-block iff m == 2n+1
          const bool dsub = (rtt == ctt) && (m == 2 * n + 1);
          if (dsub) {
#pragma unroll
            for (int r = 0; r < 16; ++r) {
              const float e = __builtin_amdgcn_exp2f(fmaf(L2E, acc1[r], -L2E));
              const int mloc = (r & 3) + 4 * lhi + 8 * (r >> 2);
              tsum += (mloc != l31) ? e : 0.0f;
            }
          } else {
#pragma unroll
            for (int r = 0; r < 16; ++r)
              tsum += __builtin_amdgcn_exp2f(fmaf(L2E, acc1[r], -L2E));
          }
        }
      }
      gsum += (rtt == ctt) ? tsum : (tsum + tsum);  // off-diag mirrored x2

      __builtin_amdgcn_s_barrier();  // buf reads done before its re-stage
      rtt = nrt;
      ctt = nct;
    }
  }

  // ---- per-block reduction -> dst[c] ----
#pragma unroll
  for (int off = 32; off; off >>= 1) gsum += __shfl_xor(gsum, off);
  if (lane == 0) wsum[wid] = gsum;
  __syncthreads();
  if (tid == 0) {
    float s = 0.0f;
#pragma unroll
    for (int q = 0; q < 8; ++q) s += wsum[q];
    dst[c] = s;
  }
}

// Real pairwise (identical to round 9: V=0, single pass)
__global__ __launch_bounds__(512, 4) void fmicl_pairwise(
    const _Float16* __restrict__ zh, float* __restrict__ pairP) {
  pairwise_body<0, 1>(zh, pairP);
}

// Diagnostic probes (x3 repetitions so each row tops the PMC table)
template <int V>
__global__ __launch_bounds__(512, 4) void fmicl_probe(
    const _Float16* __restrict__ zh, float* __restrict__ pairQ) {
  pairwise_body<V, 3>(zh, pairQ);
}

// ---------------------------------------------------------------------------
// Kernel 3: single-block fused reduce + assemble scalar. Unchanged from R9.
// ---------------------------------------------------------------------------
__global__ void fmicl_reduce(const float* __restrict__ pairP,
                             const float* __restrict__ sposB,
                             float* __restrict__ out) {
  const int t = threadIdx.x;  // 1024 threads = 16 waves
  double nsum = (t < NBLK) ? (double)pairP[t] : 0.0;
  double psum = (t < 512) ? (double)sposB[t] : 0.0;
#pragma unroll
  for (int off = 32; off; off >>= 1) {
    nsum += __shfl_xor(nsum, off);
    psum += __shfl_xor(psum, off);
  }
  __shared__ double ls[2][16];
  const int lane = t & 63;
  const int wid = t >> 6;
  if (lane == 0) {
    ls[0][wid] = nsum;
    ls[1][wid] = psum;
  }
  __syncthreads();
  if (t == 0) {
    double nn = 0.0, pp = 0.0;
#pragma unroll
    for (int q = 0; q < 16; ++q) {
      nn += ls[0][q];
      pp += ls[1][q];
    }
    const double pos_mean = pp / (double)NROWS;
    const double star_mean = nn / ((double)NROWS * (double)(NROWS - 1)) + 1e-8;
    out[0] = (float)(-pos_mean + 1.5 * star_mean);
  }
}

extern "C" void kernel_launch(void* const* d_in, const int* in_sizes, int n_in,
                              void* d_out, int out_size, void* d_ws,
                              size_t ws_size, hipStream_t stream) {
  const float* z1 = (const float*)d_in[0];
  const float* z2 = (const float*)d_in[1];
  float* out = (float*)d_out;
  char* ws = (char*)d_ws;

  // ws layout (every slot rewritten every call; no memset needed):
  //   [0)     pairP float[512]    (2048 B)
  //   [2048)  pairQ float[512]    (2048 B, probe scratch)
  //   [4096)  sposB float[512]    (2048 B)
  //   [6144)  zh    f16[8192*128] (2 MiB, 16B-aligned)
  float* pairP = (float*)(ws + 0);
  float* pairQ = (float*)(ws + 2048);
  float* sposB = (float*)(ws + 4096);
  _Float16* zh = (_Float16*)(ws + 6144);

  // ---- real computation (identical to round 9) ----
  fmicl_normalize<<<512, 1024, 0, stream>>>(z1, z2, zh, sposB);
  fmicl_pairwise<<<NBLK, 512, 0, stream>>>(zh, pairP);
  fmicl_reduce<<<1, 1024, 0, stream>>>(pairP, sposB, out);

  // ---- diagnostic probes (do not touch out; deterministic; timing-only) ----
  fmicl_probe<0><<<NBLK, 512, 0, stream>>>(zh, pairQ);  // full x3
  fmicl_probe<1><<<NBLK, 512, 0, stream>>>(zh, pairQ);  // no in-loop staging
  fmicl_probe<2><<<NBLK, 512, 0, stream>>>(zh, pairQ);  // no LDS reads
  fmicl_probe<4><<<NBLK, 512, 0, stream>>>(zh, pairQ);  // no exp2 epilogue
}

// Round 11
// 42.604 us; speedup vs baseline: 4.5337x; 4.5337x over previous
//
#include <hip/hip_runtime.h>

#define NROWS 8192
#define DIM 128
#define NT 64      // 128x128 tiles per side
#define NBLK 512   // pairwise blocks; block c owns 4(+1) consecutive tiles

typedef _Float16 f16x8 __attribute__((ext_vector_type(8)));
typedef _Float16 f16x2 __attribute__((ext_vector_type(2)));
typedef float f32x16 __attribute__((ext_vector_type(16)));

#define L2E 1.4426950408889634f  // log2(e)

#define AS1(p) ((const __attribute__((address_space(1))) void*)(p))
#define AS3(p) ((__attribute__((address_space(3))) void*)(p))

// ---------------------------------------------------------------------------
// Kernel 1: per-row L2 normalize (fp32, as reference). Unchanged (R9-verified).
// ---------------------------------------------------------------------------
__global__ __launch_bounds__(1024) void fmicl_normalize(
    const float* __restrict__ z1, const float* __restrict__ z2,
    _Float16* __restrict__ zh, float* __restrict__ sposB) {
  const int wid = threadIdx.x >> 6;
  const int lane = threadIdx.x & 63;
  const int row = blockIdx.x * 16 + wid;
  const float2 a = ((const float2*)(z1 + (size_t)row * DIM))[lane];
  const float2 b = ((const float2*)(z2 + (size_t)row * DIM))[lane];
  float s1 = a.x * a.x + a.y * a.y;
  float s2 = b.x * b.x + b.y * b.y;
#pragma unroll
  for (int off = 32; off; off >>= 1) {
    s1 += __shfl_xor(s1, off);
    s2 += __shfl_xor(s2, off);
  }
  const float inv1 = 1.0f / fmaxf(sqrtf(s1), 1e-12f);
  const float inv2 = 1.0f / fmaxf(sqrtf(s2), 1e-12f);
  const float n1x = a.x * inv1, n1y = a.y * inv1;
  const float n2x = b.x * inv2, n2y = b.y * inv2;
  const float dx = n1x - n2x, dy = n1y - n2y;
  float dp = dx * dx + dy * dy;
#pragma unroll
  for (int off = 32; off; off >>= 1) dp += __shfl_xor(dp, off);
  f16x2 h;
  h.x = (_Float16)n1x;
  h.y = (_Float16)n1y;
  *(f16x2*)(zh + (size_t)row * DIM + 2 * lane) = h;
  __shared__ float sposL[16];
  if (lane == 0)
    sposL[wid] = logf(expf(-0.5f * dp) + 1e-8f) + 1.0f;  // f'(g_pos)
  __syncthreads();
  if (threadIdx.x == 0) {
    float s = 0.0f;
#pragma unroll
    for (int k = 0; k < 16; ++k) s += sposL[k];
    sposB[blockIdx.x] = s;
  }
}

// ---------------------------------------------------------------------------
// Stage one 128-row B panel (32 KiB) into an LDS panel via global_load_lds
// width=16. LDS dest linear; global source pre-swizzled (granule col ^=
// row&15); read side applies the same XOR (involution; rounds 3-9 verified,
// 0 bank conflicts). 4 VMEM instructions per wave.
// ---------------------------------------------------------------------------
__device__ __forceinline__ void stageB(const _Float16* __restrict__ zh,
                                       _Float16* buf, int ct, int wid,
                                       int lane) {
  const _Float16* base = zh + ((size_t)ct << 7) * DIM;
#pragma unroll
  for (int it = 0; it < 4; ++it) {
    const int P = it * 8 + wid;          // wave-uniform 4-row group 0..31
    const int R = P * 4 + (lane >> 4);   // row 0..127
    const int cs = (lane & 15) ^ (R & 15);
    __builtin_amdgcn_global_load_lds(AS1(base + (size_t)R * DIM + cs * 8),
                                     AS3(buf + P * 512), 16, 0, 0);
  }
}

// Load the wave's 64 A-rows (2 chains of 32) into registers (64 VGPR).
__device__ __forceinline__ void loadA(const _Float16* __restrict__ zh, int rt,
                                      int mw, int l31, int lhi, uint4* a0,
                                      uint4* a1) {
  const uint4* r0 = (const uint4*)(zh + (size_t)((rt << 7) + mw * 64 + l31) * DIM);
  const uint4* r1 = r0 + 32 * (DIM / 8);
#pragma unroll
  for (int ks = 0; ks < 8; ++ks) {
    a0[ks] = r0[2 * ks + lhi];
    a1[ks] = r1[2 * ks + lhi];
  }
}

// One 128x128 tile: 8 K-steps of {1 ds_read_b128 -> 2 MFMA}, then the
// 3-op exp2 epilogue (g = exp2(fma(log2e,dot,-log2e)) == exp(-d2/2) for
// unit rows). Accumulates the (mirror-weighted) tile sum into gsum.
__device__ __forceinline__ void computeTile(const _Float16* __restrict__ buf,
                                            int rtt, int ctt, int mw, int nw,
                                            int l31, int lhi,
                                            const uint4* a0, const uint4* a1,
                                            float& gsum) {
  const uint4* B4 = (const uint4*)buf;
  const int rb = nw * 32 + l31;
  f32x16 acc0 = {}, acc1 = {};
#pragma unroll
  for (int ks = 0; ks < 8; ++ks) {
    const int kg = 2 * ks + lhi;
    const uint4 vb = B4[rb * 16 + (kg ^ (rb & 15))];
    const f16x8 bf = __builtin_bit_cast(f16x8, vb);
    acc0 = __builtin_amdgcn_mfma_f32_32x32x16_f16(
        __builtin_bit_cast(f16x8, a0[ks]), bf, acc0, 0, 0, 0);
    acc1 = __builtin_amdgcn_mfma_f32_32x32x16_f16(
        __builtin_bit_cast(f16x8, a1[ks]), bf, acc1, 0, 0, 0);
  }
  // C/D layout (32x32): col=lane&31, row=(reg&3)+8*(reg>>2)+4*(lane>>5)
  float tsum = 0.0f;
  {  // chain 0: rows [mw*64, +32); diag sub-block iff nw == 2*mw
    const bool dsub = (rtt == ctt) && (nw == 2 * mw);
    if (dsub) {
#pragma unroll
      for (int r = 0; r < 16; ++r) {
        const float e = __builtin_amdgcn_exp2f(fmaf(L2E, acc0[r], -L2E));
        const int mloc = (r & 3) + 4 * lhi + 8 * (r >> 2);
        tsum += (mloc != l31) ? e : 0.0f;
      }
    } else {
#pragma unroll
      for (int r = 0; r < 16; ++r)
        tsum += __builtin_amdgcn_exp2f(fmaf(L2E, acc0[r], -L2E));
    }
  }
  {  // chain 1: rows [mw*64+32, +32); diag sub-block iff nw == 2*mw+1
    const bool dsub = (rtt == ctt) && (nw == 2 * mw + 1);
    if (dsub) {
#pragma unroll
      for (int r = 0; r < 16; ++r) {
        const float e = __builtin_amdgcn_exp2f(fmaf(L2E, acc1[r], -L2E));
        const int mloc = (r & 3) + 4 * lhi + 8 * (r >> 2);
        tsum += (mloc != l31) ? e : 0.0f;
      }
    } else {
#pragma unroll
      for (int r = 0; r < 16; ++r)
        tsum += __builtin_amdgcn_exp2f(fmaf(L2E, acc1[r], -L2E));
    }
  }
  gsum += (rtt == ctt) ? tsum : (tsum + tsum);  // off-diag mirrored x2
}

// ---------------------------------------------------------------------------
// Kernel 2: chunk-deep pipeline. 512 blocks x 512 threads (8 waves, 2M x 4N;
// wave = 64 A-rows in regs x 32 B-cols from LDS -> 1 ds_read : 2 MFMA).
// All 4 B-panels (128 KiB LDS, 1 block/CU) staged in the PROLOGUE; per-panel
// counted vmcnt(12/8/4/0) + raw s_barrier (in-order vmcnt accounting, m135):
// 3 panels always in flight, barriers 1/tile (was 2/tile), and between
// barriers each wave runs a full tile independently -> waves de-phase ->
// MFMA/VALU/trans/LDS pipes overlap (m114). A-loads drained before staging
// so the manual counts are exact; band-crossing A-reload does a one-off
// vmcnt(0) (rare, correctness-safe). len-5 blocks (c%16==0) restage panel 0
// after a post-t0 barrier. XCD swizzle (bid&7)*64+bid>>3 (bijective).
// No atomics.
// ---------------------------------------------------------------------------
__global__ __launch_bounds__(512, 2) void fmicl_pairwise(
    const _Float16* __restrict__ zh, float* __restrict__ pairP) {
  __shared__ _Float16 S[4][128 * DIM];  // 4 x 32 KiB = 128 KiB
  __shared__ float wsum[8];

  const int tid = threadIdx.x;
  const int lane = tid & 63;
  const int wid = tid >> 6;
  const int l31 = lane & 31;
  const int lhi = lane >> 5;
  const int mw = wid >> 2;  // 0..1: 64-row half of the band
  const int nw = wid & 3;   // 0..3: 32-col quarter of the tile

  // XCD-chunked swizzle (512 = 8*64, bijective; 260 tiles per XCD)
  const int c = (blockIdx.x & 7) * 64 + (blockIdx.x >> 3);
  const int nx = (c + 15) >> 4;  // len-5 chunks before c
  const int base = 4 * c + nx;
  const int len = 4 + ((c & 15) == 0 ? 1 : 0);

  // ---- decode base -> (r0, c0); C(r) = r*NT - r(r-1)/2 ----
  int r0 = (int)(64.5f - sqrtf(64.5f * 64.5f - 2.0f * (float)base));
  if (r0 < 0) r0 = 0;
  while (r0 > 0 && (r0 * NT - (r0 * (r0 - 1)) / 2) > base) --r0;
  while (((r0 + 1) * NT - ((r0 + 1) * r0) / 2) <= base) ++r0;
  int c0 = r0 + (base - (r0 * NT - (r0 * (r0 - 1)) / 2));

  // ---- successor tile coords (flat triangular order) ----
  int r1 = r0, c1 = c0 + 1; if (c1 == NT) { ++r1; c1 = r1; }
  int r2 = r1, c2 = c1 + 1; if (c2 == NT) { ++r2; c2 = r2; }
  int r3 = r2, c3 = c2 + 1; if (c3 == NT) { ++r3; c3 = r3; }
  int r4 = r3, c4 = c3 + 1; if (c4 == NT) { ++r4; c4 = r4; }  // used iff len==5

  uint4 a0[8], a1[8];
  loadA(zh, r0, mw, l31, lhi, a0, a1);
  asm volatile("s_waitcnt vmcnt(0)" ::: "memory");  // A drained: counts exact

  stageB(zh, S[0], c0, wid, lane);
  stageB(zh, S[1], c1, wid, lane);
  stageB(zh, S[2], c2, wid, lane);
  stageB(zh, S[3], c3, wid, lane);

  float gsum = 0.0f;

  // ---- t0 ----
  asm volatile("s_waitcnt vmcnt(12)" ::: "memory");
  __builtin_amdgcn_s_barrier();
  computeTile(S[0], r0, c0, mw, nw, l31, lhi, a0, a1, gsum);
  if (len == 5) {
    __builtin_amdgcn_s_barrier();  // all waves done reading panel 0
    stageB(zh, S[0], c4, wid, lane);
  }
  // ---- t1 ----
  if (r1 != r0) {
    loadA(zh, r1, mw, l31, lhi, a0, a1);
    asm volatile("s_waitcnt vmcnt(0)" ::: "memory");  // rare: full drain
  }
  if (len == 5)
    asm volatile("s_waitcnt vmcnt(12)" ::: "memory");
  else
    asm volatile("s_waitcnt vmcnt(8)" ::: "memory");
  __builtin_amdgcn_s_barrier();
  computeTile(S[1], r1, c1, mw, nw, l31, lhi, a0, a1, gsum);
  // ---- t2 ----
  if (r2 != r1) {
    loadA(zh, r2, mw, l31, lhi, a0, a1);
    asm volatile("s_waitcnt vmcnt(0)" ::: "memory");
  }
  if (len == 5)
    asm volatile("s_waitcnt vmcnt(8)" ::: "memory");
  else
    asm volatile("s_waitcnt vmcnt(4)" ::: "memory");
  __builtin_amdgcn_s_barrier();
  computeTile(S[2], r2, c2, mw, nw, l31, lhi, a0, a1, gsum);
  // ---- t3 ----
  if (r3 != r2) {
    loadA(zh, r3, mw, l31, lhi, a0, a1);
    asm volatile("s_waitcnt vmcnt(0)" ::: "memory");
  }
  if (len == 5)
    asm volatile("s_waitcnt vmcnt(4)" ::: "memory");
  else
    asm volatile("s_waitcnt vmcnt(0)" ::: "memory");
  __builtin_amdgcn_s_barrier();
  computeTile(S[3], r3, c3, mw, nw, l31, lhi, a0, a1, gsum);
  // ---- t4 (len-5 blocks only) ----
  if (len == 5) {
    if (r4 != r3) loadA(zh, r4, mw, l31, lhi, a0, a1);
    asm volatile("s_waitcnt vmcnt(0)" ::: "memory");
    __builtin_amdgcn_s_barrier();
    computeTile(S[0], r4, c4, mw, nw, l31, lhi, a0, a1, gsum);
  }

  // ---- per-block reduction -> pairP[c] ----
#pragma unroll
  for (int off = 32; off; off >>= 1) gsum += __shfl_xor(gsum, off);
  if (lane == 0) wsum[wid] = gsum;
  __syncthreads();
  if (tid == 0) {
    float s = 0.0f;
#pragma unroll
    for (int q = 0; q < 8; ++q) s += wsum[q];
    pairP[c] = s;
  }
}

// ---------------------------------------------------------------------------
// Kernel 3: single-block fused reduce + assemble scalar. Unchanged.
// star_neg = g + EPS exactly, so star_mean = negSum/(N(N-1)) + EPS.
// ---------------------------------------------------------------------------
__global__ void fmicl_reduce(const float* __restrict__ pairP,
                             const float* __restrict__ sposB,
                             float* __restrict__ out) {
  const int t = threadIdx.x;  // 1024 threads = 16 waves
  double nsum = (t < NBLK) ? (double)pairP[t] : 0.0;
  double psum = (t < 512) ? (double)sposB[t] : 0.0;
#pragma unroll
  for (int off = 32; off; off >>= 1) {
    nsum += __shfl_xor(nsum, off);
    psum += __shfl_xor(psum, off);
  }
  __shared__ double ls[2][16];
  const int lane = t & 63;
  const int wid = t >> 6;
  if (lane == 0) {
    ls[0][wid] = nsum;
    ls[1][wid] = psum;
  }
  __syncthreads();
  if (t == 0) {
    double nn = 0.0, pp = 0.0;
#pragma unroll
    for (int q = 0; q < 16; ++q) {
      nn += ls[0][q];
      pp += ls[1][q];
    }
    const double pos_mean = pp / (double)NROWS;
    const double star_mean = nn / ((double)NROWS * (double)(NROWS - 1)) + 1e-8;
    out[0] = (float)(-pos_mean + 1.5 * star_mean);
  }
}

extern "C" void kernel_launch(void* const* d_in, const int* in_sizes, int n_in,
                              void* d_out, int out_size, void* d_ws,
                              size_t ws_size, hipStream_t stream) {
  const float* z1 = (const float*)d_in[0];
  const float* z2 = (const float*)d_in[1];
  float* out = (float*)d_out;
  char* ws = (char*)d_ws;

  // ws layout (every slot rewritten every call; no memset needed):
  //   [0)     pairP float[512]    (2048 B, pad to 4096)
  //   [4096)  sposB float[512]    (2048 B)
  //   [6144)  zh    f16[8192*128] (2 MiB, 16B-aligned)
  float* pairP = (float*)(ws + 0);
  float* sposB = (float*)(ws + 4096);
  _Float16* zh = (_Float16*)(ws + 6144);

  fmicl_normalize<<<512, 1024, 0, stream>>>(z1, z2, zh, sposB);
  fmicl_pairwise<<<NBLK, 512, 0, stream>>>(zh, pairP);
  fmicl_reduce<<<1, 1024, 0, stream>>>(pairP, sposB, out);
}

// Round 12
// 40.456 us; speedup vs baseline: 4.7744x; 1.0531x over previous
//
#include <hip/hip_runtime.h>

#define NROWS 8192
#define DIM 128
#define NBLK 1040  // 4160 rect tiles (64M x 128N, nj >= mi>>1), 4 per block

typedef _Float16 f16x8 __attribute__((ext_vector_type(8)));
typedef _Float16 f16x2 __attribute__((ext_vector_type(2)));
typedef float f32x16 __attribute__((ext_vector_type(16)));

#define L2E 1.4426950408889634f  // log2(e)

#define AS1(p) ((const __attribute__((address_space(1))) void*)(p))
#define AS3(p) ((__attribute__((address_space(3))) void*)(p))

// ---------------------------------------------------------------------------
// Kernel 1: per-row L2 normalize (fp32, as reference). Unchanged (verified).
// ---------------------------------------------------------------------------
__global__ __launch_bounds__(1024) void fmicl_normalize(
    const float* __restrict__ z1, const float* __restrict__ z2,
    _Float16* __restrict__ zh, float* __restrict__ sposB) {
  const int wid = threadIdx.x >> 6;
  const int lane = threadIdx.x & 63;
  const int row = blockIdx.x * 16 + wid;
  const float2 a = ((const float2*)(z1 + (size_t)row * DIM))[lane];
  const float2 b = ((const float2*)(z2 + (size_t)row * DIM))[lane];
  float s1 = a.x * a.x + a.y * a.y;
  float s2 = b.x * b.x + b.y * b.y;
#pragma unroll
  for (int off = 32; off; off >>= 1) {
    s1 += __shfl_xor(s1, off);
    s2 += __shfl_xor(s2, off);
  }
  const float inv1 = 1.0f / fmaxf(sqrtf(s1), 1e-12f);
  const float inv2 = 1.0f / fmaxf(sqrtf(s2), 1e-12f);
  const float n1x = a.x * inv1, n1y = a.y * inv1;
  const float n2x = b.x * inv2, n2y = b.y * inv2;
  const float dx = n1x - n2x, dy = n1y - n2y;
  float dp = dx * dx + dy * dy;
#pragma unroll
  for (int off = 32; off; off >>= 1) dp += __shfl_xor(dp, off);
  f16x2 h;
  h.x = (_Float16)n1x;
  h.y = (_Float16)n1y;
  *(f16x2*)(zh + (size_t)row * DIM + 2 * lane) = h;
  __shared__ float sposL[16];
  if (lane == 0)
    sposL[wid] = logf(expf(-0.5f * dp) + 1e-8f) + 1.0f;  // f'(g_pos)
  __syncthreads();
  if (threadIdx.x == 0) {
    float s = 0.0f;
#pragma unroll
    for (int k = 0; k < 16; ++k) s += sposL[k];
    sposB[blockIdx.x] = s;
  }
}

// tiles before band mi:  C(mi) = 64*mi - s(mi),  s = sum_{m<mi} (m>>1)
__device__ __forceinline__ int cfun(int mi) {
  const int h = mi >> 1;
  return 64 * mi - (h * h - ((mi & 1) ? 0 : h));
}

// Stage the wave's PRIVATE 8 KiB B-slice (32 zh rows) via global_load_lds
// width=16. LDS dest linear (wave-uniform base + lane*16); global source
// pre-swizzled (granule ^= row&15); read applies the same XOR (involution,
// rounds 3-11 verified, 0 bank conflicts). 8 VMEM instructions.
__device__ __forceinline__ void stageSlice(const _Float16* __restrict__ zh,
                                           _Float16* slice, int gj0,
                                           int lane) {
#pragma unroll
  for (int it = 0; it < 8; ++it) {
    const int R = it * 4 + (lane >> 4);  // row within slice 0..31
    const int cs = (lane & 15) ^ (R & 15);
    __builtin_amdgcn_global_load_lds(
        AS1(zh + (size_t)(gj0 + R) * DIM + cs * 8), AS3(slice + it * 512), 16,
        0, 0);
  }
}

// Load the wave's 64 A-rows (2 chains of 32) into registers (64 VGPR).
__device__ __forceinline__ void loadA(const _Float16* __restrict__ zh, int mi,
                                      int l31, int lhi, uint4* a0, uint4* a1) {
  const uint4* r0 = (const uint4*)(zh + (size_t)((mi << 6) + l31) * DIM);
  const uint4* r1 = r0 + 32 * (DIM / 8);
#pragma unroll
  for (int ks = 0; ks < 8; ++ks) {
    a0[ks] = r0[2 * ks + lhi];
    a1[ks] = r1[2 * ks + lhi];
  }
}

// ---------------------------------------------------------------------------
// Kernel 2: barrier-free pairwise. 1040 blocks x 256 threads (4 waves).
// Rect tile 64M x 128N; wave owns 64M x 32N with a PRIVATE double-buffered
// 8 KiB B-slice -> the only sync a wave needs is its own counted vmcnt; NO
// s_barrier in the loop, waves free-run and de-phase so LDS/VALU/MFMA/L2
// overlap across the 8 resident waves/CU. Per K-step: 1 ds_read_b128 -> 2
// MFMA (A in regs). Block c owns 4 consecutive tiles of the flat band-major
// list {(mi,nj): nj >= mi>>1} (4160 = 4*1040, perfectly balanced).
// vmcnt ledger: stage=8, A-reload=16, A issued before stage -> vmcnt(8)
// covers stage(t)+A; vmcnt(0) on the last tile.
// Sum = strict-upper g only (per-element j>i mask on diagonal-crossing tiles
// nj==mi>>1, uniform fast path elsewhere); reduce multiplies by 2.
// Epilogue: g = exp2(fma(log2e,dot,-log2e)) == exp(-d2/2) for unit rows.
// XCD swizzle (bid&7)*130 + bid>>3 (1040 = 8*130, bijective). No atomics.
// ---------------------------------------------------------------------------
__global__ __launch_bounds__(256, 2) void fmicl_pairwise(
    const _Float16* __restrict__ zh, float* __restrict__ pairP) {
  __shared__ _Float16 S[2][4][4096];  // 2 buf x 4 waves x 8 KiB = 64 KiB
  __shared__ float wsum[4];

  const int tid = threadIdx.x;
  const int lane = tid & 63;
  const int nw = tid >> 6;  // wave id == private N-slice id (cols nw*32..+32)
  const int l31 = lane & 31;
  const int lhi = lane >> 5;

  // XCD-chunked swizzle (1040 = 8*130, bijective)
  const int cid = (blockIdx.x & 7) * 130 + (blockIdx.x >> 3);
  const int base = cid * 4;

  // ---- decode base -> (mi, nj): estimate from 64m - m^2/4, then correct ----
  int mi;
  {
    const float arg = fmaxf(0.0f, 4096.0f - (float)base);
    mi = (int)(2.0f * (64.0f - sqrtf(arg)));
    mi = mi < 0 ? 0 : (mi > 127 ? 127 : mi);
    while (mi > 0 && cfun(mi) > base) --mi;
    while (mi < 127 && cfun(mi + 1) <= base) ++mi;
  }
  int nj = (mi >> 1) + (base - cfun(mi));

  uint4 a0[8], a1[8];
  loadA(zh, mi, l31, lhi, a0, a1);                   // 16 loads
  stageSlice(zh, S[0][nw], 128 * nj + 32 * nw, lane);  // 8 loads

  float gsum = 0.0f;
#pragma unroll 1
  for (int t = 0; t < 4; ++t) {
    // successor tile coords (band-major flat order)
    int mi2 = mi, nj2 = nj + 1;
    if (nj2 == 64) { ++mi2; nj2 = mi2 >> 1; }

    if (t < 3) {
      stageSlice(zh, S[(t + 1) & 1][nw], 128 * nj2 + 32 * nw, lane);
      // oldest (stage(t) [+ A-reload]) complete; stage(t+1) stays in flight
      asm volatile("s_waitcnt vmcnt(8)" ::: "memory");
    } else {
      asm volatile("s_waitcnt vmcnt(0)" ::: "memory");
    }

    // ---- compute: 8 K-steps, 1 private ds_read -> 2 MFMA ----
    const uint4* B4 = (const uint4*)S[t & 1][nw];
    f32x16 acc0 = {}, acc1 = {};
#pragma unroll
    for (int ks = 0; ks < 8; ++ks) {
      const int kg = 2 * ks + lhi;
      const uint4 vb = B4[l31 * 16 + (kg ^ (l31 & 15))];
      const f16x8 bf = __builtin_bit_cast(f16x8, vb);
      acc0 = __builtin_amdgcn_mfma_f32_32x32x16_f16(
          __builtin_bit_cast(f16x8, a0[ks]), bf, acc0, 0, 0, 0);
      acc1 = __builtin_amdgcn_mfma_f32_32x32x16_f16(
          __builtin_bit_cast(f16x8, a1[ks]), bf, acc1, 0, 0, 0);
    }

    // ---- epilogue: strict-upper only; crossing tiles mask per element ----
    // C/D layout (32x32): col=lane&31, row=(reg&3)+8*(reg>>2)+4*(lane>>5)
    const int jj = 128 * nj + 32 * nw + l31;
    float tsum = 0.0f;
    if (nj == (mi >> 1)) {  // diagonal-crossing tile (block-uniform)
      const int ii0 = (mi << 6) + 4 * lhi;
#pragma unroll
      for (int r = 0; r < 16; ++r) {
        const float e0 = __builtin_amdgcn_exp2f(fmaf(L2E, acc0[r], -L2E));
        const float e1 = __builtin_amdgcn_exp2f(fmaf(L2E, acc1[r], -L2E));
        const int mo = (r & 3) + 8 * (r >> 2);
        tsum += (jj > ii0 + mo) ? e0 : 0.0f;
        tsum += (jj > ii0 + 32 + mo) ? e1 : 0.0f;
      }
    } else {  // pure-upper tile: branchless
#pragma unroll
      for (int r = 0; r < 16; ++r) {
        tsum += __builtin_amdgcn_exp2f(fmaf(L2E, acc0[r], -L2E));
        tsum += __builtin_amdgcn_exp2f(fmaf(L2E, acc1[r], -L2E));
      }
    }
    gsum += tsum;

    // A-reload for next tile AFTER this tile's MFMAs (next vmcnt(8) covers it)
    if (t < 3 && mi2 != mi) loadA(zh, mi2, l31, lhi, a0, a1);
    mi = mi2;
    nj = nj2;
  }

  // ---- per-block reduction -> pairP[cid] (one syncthreads, post-loop) ----
#pragma unroll
  for (int off = 32; off; off >>= 1) gsum += __shfl_xor(gsum, off);
  if (lane == 0) wsum[nw] = gsum;
  __syncthreads();
  if (tid == 0) pairP[cid] = wsum[0] + wsum[1] + wsum[2] + wsum[3];
}

// ---------------------------------------------------------------------------
// Kernel 3: single-block fused reduce + assemble scalar (deterministic
// fixed-order tree). pairP holds strict-upper sums -> ordered sum = 2x.
// star_neg = g + EPS exactly, so star_mean = 2*negSum/(N(N-1)) + EPS.
// ---------------------------------------------------------------------------
__global__ void fmicl_reduce(const float* __restrict__ pairP,
                             const float* __restrict__ sposB,
                             float* __restrict__ out) {
  const int t = threadIdx.x;  // 1024 threads = 16 waves
  double nsum = (double)pairP[t] + ((t < NBLK - 1024) ? (double)pairP[t + 1024] : 0.0);
  double psum = (t < 512) ? (double)sposB[t] : 0.0;
#pragma unroll
  for (int off = 32; off; off >>= 1) {
    nsum += __shfl_xor(nsum, off);
    psum += __shfl_xor(psum, off);
  }
  __shared__ double ls[2][16];
  const int lane = t & 63;
  const int wid = t >> 6;
  if (lane == 0) {
    ls[0][wid] = nsum;
    ls[1][wid] = psum;
  }
  __syncthreads();
  if (t == 0) {
    double nn = 0.0, pp = 0.0;
#pragma unroll
    for (int q = 0; q < 16; ++q) {
      nn += ls[0][q];
      pp += ls[1][q];
    }
    const double pos_mean = pp / (double)NROWS;
    const double star_mean =
        2.0 * nn / ((double)NROWS * (double)(NROWS - 1)) + 1e-8;
    out[0] = (float)(-pos_mean + 1.5 * star_mean);
  }
}

extern "C" void kernel_launch(void* const* d_in, const int* in_sizes, int n_in,
                              void* d_out, int out_size, void* d_ws,
                              size_t ws_size, hipStream_t stream) {
  const float* z1 = (const float*)d_in[0];
  const float* z2 = (const float*)d_in[1];
  float* out = (float*)d_out;
  char* ws = (char*)d_ws;

  // ws layout (every slot rewritten every call; no memset needed):
  //   [0)     pairP float[1040]   (4160 B, pad to 6144)
  //   [6144)  sposB float[512]    (2048 B)
  //   [8192)  zh    f16[8192*128] (2 MiB, 16B-aligned)
  float* pairP = (float*)(ws + 0);
  float* sposB = (float*)(ws + 6144);
  _Float16* zh = (_Float16*)(ws + 8192);

  fmicl_normalize<<<512, 1024, 0, stream>>>(z1, z2, zh, sposB);
  fmicl_pairwise<<<NBLK, 256, 0, stream>>>(zh, pairP);
  fmicl_reduce<<<1, 1024, 0, stream>>>(pairP, sposB, out);
}